// Round 9
// baseline (186.420 us; speedup 1.0000x reference)
//
#include <hip/hip_runtime.h>

#define N 8192
#define D 256
#define BM 128                    // I-tile rows
#define BJ 64                     // J-tile rows
#define JG 4                      // J-tiles per block
#define GJ (N / BJ / JG)          // 32
#define GI (N / BM)               // 64
#define NBLK (GJ * GI)            // 2048

typedef int   i32x4 __attribute__((ext_vector_type(4)));
typedef int   i32x8 __attribute__((ext_vector_type(8)));
typedef float f32x4 __attribute__((ext_vector_type(4)));
typedef float f32x2 __attribute__((ext_vector_type(2)));

// -------- prep: fp32 -> fp8 e4m3 (packed), norms of the DEQUANTIZED values ----
__device__ __forceinline__ unsigned pack_fp8x4(float a, float b, float c, float d) {
    unsigned lo = __builtin_amdgcn_cvt_pk_fp8_f32(a, b, 0, false);
    return __builtin_amdgcn_cvt_pk_fp8_f32(c, d, lo, true);
}
__device__ __forceinline__ float dequant_sumsq(unsigned q) {
    const float v0 = __builtin_amdgcn_cvt_f32_fp8(q, 0);
    const float v1 = __builtin_amdgcn_cvt_f32_fp8(q, 1);
    const float v2 = __builtin_amdgcn_cvt_f32_fp8(q, 2);
    const float v3 = __builtin_amdgcn_cvt_f32_fp8(q, 3);
    return fmaf(v0, v0, fmaf(v1, v1, fmaf(v2, v2, v3 * v3)));
}

// one wave per row (2048 blocks); block 0 zeroes the reduction cells
__global__ void prep_kernel(const float* __restrict__ x1, const float* __restrict__ x2,
                            unsigned* __restrict__ x1q, unsigned* __restrict__ x2q,
                            unsigned* __restrict__ pq,
                            float* __restrict__ sq1, float* __restrict__ sq2,
                            float* __restrict__ sqp, double* __restrict__ acc,
                            unsigned* __restrict__ ctr) {
    const int tid = threadIdx.x, lane = tid & 63, wv = tid >> 6;
    const int row = blockIdx.x * 4 + wv;
    if (blockIdx.x == 0 && tid == 0) { *acc = 0.0; *ctr = 0u; }
    const size_t eb = (size_t)row * D + lane * 4;
    const float4 a = *(const float4*)(x1 + eb);
    const float4 b = *(const float4*)(x2 + eb);
    const float px = 0.5f * (a.x + b.x), py = 0.5f * (a.y + b.y);
    const float pz = 0.5f * (a.z + b.z), pw = 0.5f * (a.w + b.w);
    const unsigned qa = pack_fp8x4(a.x, a.y, a.z, a.w);
    const unsigned qb = pack_fp8x4(b.x, b.y, b.z, b.w);
    const unsigned qp = pack_fp8x4(px, py, pz, pw);
    const size_t wb = (size_t)row * (D / 4) + lane;
    x1q[wb] = qa; x2q[wb] = qb; pq[wb] = qp;
    float s1 = dequant_sumsq(qa), s2 = dequant_sumsq(qb), sp = dequant_sumsq(qp);
    #pragma unroll
    for (int o = 32; o > 0; o >>= 1) {
        s1 += __shfl_down(s1, o, 64);
        s2 += __shfl_down(s2, o, 64);
        sp += __shfl_down(sp, o, 64);
    }
    if (lane == 0) { sq1[row] = s1; sq2[row] = s2; sqp[row] = sp; }
}

// -------- main ---------------------------------------------------------------
__device__ __forceinline__ f32x4 mfma8(i32x8 a, i32x8 b, f32x4 c) {
    return __builtin_amdgcn_mfma_scale_f32_16x16x128_f8f6f4(
        a, b, c, 0, 0, 0, 0x7F7F7F7F, 0, 0x7F7F7F7F);
}

// fragment: 32 fp8 (k-chunk quad*32) of row m; 16B blocks XOR-swizzled by row&7
__device__ __forceinline__ i32x8 read_frag(const unsigned char* Ts, int m, int quad) {
    const int r7 = m & 7;
    const i32x4 lo = *(const i32x4*)(Ts + m * 128 + ((((2 * quad)     ^ r7)) << 4));
    const i32x4 hi = *(const i32x4*)(Ts + m * 128 + ((((2 * quad + 1) ^ r7)) << 4));
    i32x8 f;
    f[0] = lo[0]; f[1] = lo[1]; f[2] = lo[2]; f[3] = lo[3];
    f[4] = hi[0]; f[5] = hi[1]; f[6] = hi[2]; f[7] = hi[3];
    return f;
}

// stage a 128-row x 128B K-chunk (16 KB, 16 groups)
__device__ __forceinline__ void stageA(const unsigned char* __restrict__ g,
                                       unsigned char* s, int rowbase, size_t kb,
                                       int wv, int srow, int sblk) {
    #pragma unroll
    for (int it = 0; it < 4; ++it) {
        const int grp = wv * 4 + it;
        const int row = grp * 8 + srow;
        __builtin_amdgcn_global_load_lds(
            (const __attribute__((address_space(1))) void*)(g + (size_t)(rowbase + row) * D + kb + sblk * 16),
            (__attribute__((address_space(3))) void*)(s + grp * 1024), 16, 0, 0);
    }
}
// stage a 64-row x 128B K-chunk (8 KB, 8 groups)
__device__ __forceinline__ void stageB(const unsigned char* __restrict__ g,
                                       unsigned char* s, int rowbase, size_t kb,
                                       int wv, int srow, int sblk) {
    #pragma unroll
    for (int it = 0; it < 2; ++it) {
        const int grp = wv * 2 + it;
        const int row = grp * 8 + srow;
        __builtin_amdgcn_global_load_lds(
            (const __attribute__((address_space(1))) void*)(g + (size_t)(rowbase + row) * D + kb + sblk * 16),
            (__attribute__((address_space(3))) void*)(s + grp * 1024), 16, 0, 0);
    }
}

// packed-f32 log-sum over this thread's 32 entries (4 ti x 2 tj x 4 regs)
__device__ __forceinline__ float logsumP(const f32x4 (&acc)[4][2],
                                         const float* __restrict__ sqA,
                                         const float sb[2], int wr, int quad) {
    float s = 0.0f;
    #pragma unroll
    for (int ti = 0; ti < 4; ++ti) {
        const int base = wr * 64 + ti * 16 + quad * 4;
        const f32x2 sa01 = {sqA[base], sqA[base + 1]};
        const f32x2 sa23 = {sqA[base + 2], sqA[base + 3]};
        f32x2 pr = {1.0f, 1.0f};
        #pragma unroll
        for (int tj = 0; tj < 2; ++tj) {
            const f32x2 sbv = {sb[tj], sb[tj]};
            const f32x2 t01 = sa01 + sbv, t23 = sa23 + sbv;
            const f32x2 v01 = {acc[ti][tj][0], acc[ti][tj][1]};
            const f32x2 v23 = {acc[ti][tj][2], acc[ti][tj][3]};
            f32x2 d01 = t01 - 2.0f * v01;
            f32x2 d23 = t23 - 2.0f * v23;
            d01 = __builtin_elementwise_max(d01, (f32x2){1.0f, 1.0f});
            d23 = __builtin_elementwise_max(d23, (f32x2){1.0f, 1.0f});
            pr *= d01; pr *= d23;
        }
        s += __logf(pr.x * pr.y);   // product of 8 dists <= (1.5e3)^8, fp32-safe
    }
    return s;
}

// diagonal-straddling tile: per-entry weight 2 (j>i) / 1 (j==i) / 0 (j<i)
__device__ __forceinline__ float logsumStraddle(const f32x4 (&acc)[4][2],
                                                const float* __restrict__ sqA,
                                                const float sb[2],
                                                int wr, int wc, int quad, int l15,
                                                int I0, int J0) {
    float s = 0.0f;
    #pragma unroll
    for (int ti = 0; ti < 4; ++ti) {
        #pragma unroll
        for (int tj = 0; tj < 2; ++tj) {
            const int j = J0 + wc * 32 + tj * 16 + l15;
            float pr = 1.0f;
            #pragma unroll
            for (int r = 0; r < 4; ++r) {
                const int i = I0 + wr * 64 + ti * 16 + quad * 4 + r;
                float d = fmaf(-2.0f, acc[ti][tj][r],
                               sqA[wr * 64 + ti * 16 + quad * 4 + r] + sb[tj]);
                d = fmaxf(d, 1.0f);
                const float t = (j > i) ? d : 1.0f;
                const float u = (j >= i) ? d : 1.0f;
                pr *= t * u;
            }
            s += __logf(pr);
        }
    }
    return s;
}

__global__ __launch_bounds__(256) void mqjs_main(
    const unsigned char* __restrict__ x1q, const unsigned char* __restrict__ x2q,
    const unsigned char* __restrict__ pq,
    const float* __restrict__ sq1, const float* __restrict__ sq2,
    const float* __restrict__ sqp, double* __restrict__ acc_out,
    unsigned* __restrict__ ctr, float* __restrict__ out) {

    // ~49 KB LDS -> 3 blocks/CU (3 waves/SIMD)
    __shared__ __align__(16) unsigned char A2s[2 * BM * 128]; // x2 I-tile, both kc (32 KB)
    __shared__ __align__(16) unsigned char Bs [2 * BJ * 128]; // shared J-tile buffer (16 KB)
    __shared__ float sqa1[BM], sqa2[BM];
    __shared__ float red[4];

    const int tid = threadIdx.x;
    const int lane = tid & 63;
    const int wv = tid >> 6;
    const int wr = wv >> 1, wc = wv & 1;      // wave quadrant: 64 I-rows x 32 J-cols
    const int quad = lane >> 4, l15 = lane & 15;

    const int I0 = blockIdx.y * BM;
    const int jbase = blockIdx.x * JG;
    const float wse = -(float)N / (float)(N - 1);

    const int srow = lane >> 3;
    const int sblk = (lane & 7) ^ srow;

    // init: x1-I via A2s (temp) -> a1f regs; p[j0] into Bs
    stageA(x1q, A2s,         I0, 0,   wv, srow, sblk);
    stageA(x1q, A2s + 16384, I0, 128, wv, srow, sblk);
    stageB(pq,  Bs,          jbase * BJ, 0,   wv, srow, sblk);
    stageB(pq,  Bs + 8192,   jbase * BJ, 128, wv, srow, sblk);
    if (tid < BM) sqa1[tid] = sq1[I0 + tid];
    else          sqa2[tid - BM] = sq2[I0 + tid - BM];
    __syncthreads();

    i32x8 a1f[2][4];
    #pragma unroll
    for (int kc = 0; kc < 2; ++kc)
        #pragma unroll
        for (int ti = 0; ti < 4; ++ti)
            a1f[kc][ti] = read_frag(A2s + kc * 16384, wr * 64 + ti * 16 + l15, quad);
    __syncthreads();                          // all a1f reads drained
    stageA(x2q, A2s,         I0, 0,   wv, srow, sblk);
    stageA(x2q, A2s + 16384, I0, 128, wv, srow, sblk);
    __syncthreads();                          // x2-I + p[j0] resident

    float tsum = 0.0f;

    for (int jj = 0; jj < JG; ++jj) {
        const int J0 = (jbase + jj) * BJ;
        const bool doSym = (J0 >= I0);
        const bool full  = (J0 >= I0 + BM);

        // ---- pass A: acc0 = x1.p^T, acc1 = x2.p^T (Bs holds p[jj])
        f32x4 acc0[4][2], acc1[4][2], acc2[4][2];
        #pragma unroll
        for (int a = 0; a < 4; ++a)
            #pragma unroll
            for (int b = 0; b < 2; ++b) {
                acc0[a][b] = (f32x4){0.f, 0.f, 0.f, 0.f};
                acc1[a][b] = (f32x4){0.f, 0.f, 0.f, 0.f};
            }
        #pragma unroll
        for (int kc = 0; kc < 2; ++kc) {
            i32x8 bfr[2];
            #pragma unroll
            for (int tj = 0; tj < 2; ++tj)
                bfr[tj] = read_frag(Bs + kc * 8192, wc * 32 + tj * 16 + l15, quad);
            #pragma unroll
            for (int ti = 0; ti < 4; ++ti) {
                const i32x8 a2 = read_frag(A2s + kc * 16384, wr * 64 + ti * 16 + l15, quad);
                #pragma unroll
                for (int tj = 0; tj < 2; ++tj) {
                    acc0[ti][tj] = mfma8(a1f[kc][ti], bfr[tj], acc0[ti][tj]);
                    acc1[ti][tj] = mfma8(a2,          bfr[tj], acc1[ti][tj]);
                }
            }
        }
        __syncthreads();                      // all waves done reading Bs

        if (doSym) {                          // restage Bs with x1[jj]; epilogue hides flight
            stageB(x1q, Bs,        J0, 0,   wv, srow, sblk);
            stageB(x1q, Bs + 8192, J0, 128, wv, srow, sblk);
        }
        {
            float sbp[2];
            #pragma unroll
            for (int tj = 0; tj < 2; ++tj) sbp[tj] = sqp[J0 + wc * 32 + tj * 16 + l15];
            tsum += 0.5f * logsumP(acc0, sqa1, sbp, wr, quad);
            tsum += 0.5f * logsumP(acc1, sqa2, sbp, wr, quad);
        }

        // ---- pass B: acc2 = x1.x1^T (upper half)
        if (doSym) {
            __syncthreads();                  // x1[jj] staged
            #pragma unroll
            for (int a = 0; a < 4; ++a)
                #pragma unroll
                for (int b = 0; b < 2; ++b)
                    acc2[a][b] = (f32x4){0.f, 0.f, 0.f, 0.f};
            #pragma unroll
            for (int kc = 0; kc < 2; ++kc) {
                i32x8 bfr[2];
                #pragma unroll
                for (int tj = 0; tj < 2; ++tj)
                    bfr[tj] = read_frag(Bs + kc * 8192, wc * 32 + tj * 16 + l15, quad);
                #pragma unroll
                for (int ti = 0; ti < 4; ++ti)
                    #pragma unroll
                    for (int tj = 0; tj < 2; ++tj)
                        acc2[ti][tj] = mfma8(a1f[kc][ti], bfr[tj], acc2[ti][tj]);
            }
            __syncthreads();                  // all waves done reading Bs
        }

        if (jj < JG - 1) {                    // restage Bs with p[jj+1]; epilogue hides flight
            stageB(pq, Bs,        (jbase + jj + 1) * BJ, 0,   wv, srow, sblk);
            stageB(pq, Bs + 8192, (jbase + jj + 1) * BJ, 128, wv, srow, sblk);
        }
        if (doSym) {
            float sbx[2];
            #pragma unroll
            for (int tj = 0; tj < 2; ++tj) sbx[tj] = sq1[J0 + wc * 32 + tj * 16 + l15];
            if (full)
                tsum += wse * logsumP(acc2, sqa1, sbx, wr, quad);
            else
                tsum += 0.5f * wse * logsumStraddle(acc2, sqa1, sbx, wr, wc, quad, l15, I0, J0);
        }
        __syncthreads();                      // p[jj+1] staged for next iteration
    }

    // ---- block reduce + last-block finalize ----------------------------------
    #pragma unroll
    for (int o = 32; o > 0; o >>= 1) tsum += __shfl_down(tsum, o, 64);
    if (lane == 0) red[wv] = tsum;
    __syncthreads();
    if (tid == 0) {
        atomicAdd(acc_out, (double)(red[0] + red[1] + red[2] + red[3]));
        __threadfence();
        const unsigned prev = atomicAdd(ctr, 1u);
        if (prev == NBLK - 1) {
            __threadfence();
            const double tot = atomicAdd(acc_out, 0.0);   // coherent read of final sum
            out[0] = (float)(tot / (double)N);
        }
    }
}

extern "C" void kernel_launch(void* const* d_in, const int* in_sizes, int n_in,
                              void* d_out, int out_size, void* d_ws, size_t ws_size,
                              hipStream_t stream) {
    const float* x1 = (const float*)d_in[0];
    const float* x2 = (const float*)d_in[1];

    char* ws = (char*)d_ws;
    const size_t MBYTES = (size_t)N * D;                  // 2 MiB per fp8 matrix
    unsigned* x1q = (unsigned*)(ws);
    unsigned* x2q = (unsigned*)(ws + MBYTES);
    unsigned* pq  = (unsigned*)(ws + 2 * MBYTES);
    float* sq1 = (float*)(ws + 3 * MBYTES);
    float* sq2 = (float*)(ws + 3 * MBYTES + (size_t)N * 4);
    float* sqp = (float*)(ws + 3 * MBYTES + (size_t)N * 8);
    double* acc = (double*)(ws + 3 * MBYTES + (size_t)N * 12);
    unsigned* ctr = (unsigned*)(ws + 3 * MBYTES + (size_t)N * 12 + 16);

    prep_kernel<<<N / 4, 256, 0, stream>>>(x1, x2, x1q, x2q, pq, sq1, sq2, sqp, acc, ctr);
    mqjs_main<<<dim3(GJ, GI), 256, 0, stream>>>(
        (const unsigned char*)x1q, (const unsigned char*)x2q, (const unsigned char*)pq,
        sq1, sq2, sqp, acc, ctr, (float*)d_out);
}

// Round 10
// 166.339 us; speedup vs baseline: 1.1207x; 1.1207x over previous
//
#include <hip/hip_runtime.h>

#define N 8192
#define D 256
#define BM 128                    // I-tile rows
#define BJ 64                     // J-tile rows
#define JG 8                      // J-tiles per block
#define GJ (N / BJ / JG)          // 16
#define GI (N / BM)               // 64  -> grid 1024 blocks

typedef int   i32x4 __attribute__((ext_vector_type(4)));
typedef int   i32x8 __attribute__((ext_vector_type(8)));
typedef float f32x4 __attribute__((ext_vector_type(4)));
typedef float f32x2 __attribute__((ext_vector_type(2)));

// -------- prep: fp32 -> fp8 e4m3 (packed), norms of the DEQUANTIZED values ----
__device__ __forceinline__ unsigned pack_fp8x4(float a, float b, float c, float d) {
    unsigned lo = __builtin_amdgcn_cvt_pk_fp8_f32(a, b, 0, false);
    return __builtin_amdgcn_cvt_pk_fp8_f32(c, d, lo, true);
}
__device__ __forceinline__ float dequant_sumsq(unsigned q) {
    const float v0 = __builtin_amdgcn_cvt_f32_fp8(q, 0);
    const float v1 = __builtin_amdgcn_cvt_f32_fp8(q, 1);
    const float v2 = __builtin_amdgcn_cvt_f32_fp8(q, 2);
    const float v3 = __builtin_amdgcn_cvt_f32_fp8(q, 3);
    return fmaf(v0, v0, fmaf(v1, v1, fmaf(v2, v2, v3 * v3)));
}

__global__ void prep_kernel(const float* __restrict__ x1, const float* __restrict__ x2,
                            unsigned* __restrict__ x1q, unsigned* __restrict__ x2q,
                            unsigned* __restrict__ pq,
                            float* __restrict__ sq1, float* __restrict__ sq2,
                            float* __restrict__ sqp) {
    const int tid = threadIdx.x, lane = tid & 63, wv = tid >> 6;
    const int row = blockIdx.x * 4 + wv;
    const size_t eb = (size_t)row * D + lane * 4;
    const float4 a = *(const float4*)(x1 + eb);
    const float4 b = *(const float4*)(x2 + eb);
    const float px = 0.5f * (a.x + b.x), py = 0.5f * (a.y + b.y);
    const float pz = 0.5f * (a.z + b.z), pw = 0.5f * (a.w + b.w);
    const unsigned qa = pack_fp8x4(a.x, a.y, a.z, a.w);
    const unsigned qb = pack_fp8x4(b.x, b.y, b.z, b.w);
    const unsigned qp = pack_fp8x4(px, py, pz, pw);
    const size_t wb = (size_t)row * (D / 4) + lane;
    x1q[wb] = qa; x2q[wb] = qb; pq[wb] = qp;
    float s1 = dequant_sumsq(qa), s2 = dequant_sumsq(qb), sp = dequant_sumsq(qp);
    #pragma unroll
    for (int o = 32; o > 0; o >>= 1) {
        s1 += __shfl_down(s1, o, 64);
        s2 += __shfl_down(s2, o, 64);
        sp += __shfl_down(sp, o, 64);
    }
    if (lane == 0) { sq1[row] = s1; sq2[row] = s2; sqp[row] = sp; }
}

// -------- main ---------------------------------------------------------------
__device__ __forceinline__ f32x4 mfma8(i32x8 a, i32x8 b, f32x4 c) {
    return __builtin_amdgcn_mfma_scale_f32_16x16x128_f8f6f4(
        a, b, c, 0, 0, 0, 0x7F7F7F7F, 0, 0x7F7F7F7F);
}

// B-fragment from LDS: 32 fp8 (k-chunk quad*32) of row m; 16B blocks XOR-swizzled by row&7
__device__ __forceinline__ i32x8 read_frag(const unsigned char* Ts, int m, int quad) {
    const int r7 = m & 7;
    const i32x4 lo = *(const i32x4*)(Ts + m * 128 + ((((2 * quad)     ^ r7)) << 4));
    const i32x4 hi = *(const i32x4*)(Ts + m * 128 + ((((2 * quad + 1) ^ r7)) << 4));
    i32x8 f;
    f[0] = lo[0]; f[1] = lo[1]; f[2] = lo[2]; f[3] = lo[3];
    f[4] = hi[0]; f[5] = hi[1]; f[6] = hi[2]; f[7] = hi[3];
    return f;
}

// stage a 64-row x 128B K-chunk (8 KB, 8 groups)
__device__ __forceinline__ void stageB(const unsigned char* __restrict__ g,
                                       unsigned char* s, int rowbase, size_t kb,
                                       int wv, int srow, int sblk) {
    #pragma unroll
    for (int it = 0; it < 2; ++it) {
        const int grp = wv * 2 + it;
        const int row = grp * 8 + srow;
        __builtin_amdgcn_global_load_lds(
            (const __attribute__((address_space(1))) void*)(g + (size_t)(rowbase + row) * D + kb + sblk * 16),
            (__attribute__((address_space(3))) void*)(s + grp * 1024), 16, 0, 0);
    }
}

// packed-f32 log-sum over this thread's 32 entries (4 ti x 2 tj x 4 regs)
__device__ __forceinline__ float logsumP(const f32x4 (&acc)[4][2],
                                         const float* __restrict__ sqA,
                                         const float sb[2], int wr, int quad) {
    float s = 0.0f;
    #pragma unroll
    for (int ti = 0; ti < 4; ++ti) {
        const int base = wr * 64 + ti * 16 + quad * 4;
        const f32x2 sa01 = {sqA[base], sqA[base + 1]};
        const f32x2 sa23 = {sqA[base + 2], sqA[base + 3]};
        f32x2 pr = {1.0f, 1.0f};
        #pragma unroll
        for (int tj = 0; tj < 2; ++tj) {
            const f32x2 sbv = {sb[tj], sb[tj]};
            const f32x2 t01 = sa01 + sbv, t23 = sa23 + sbv;
            const f32x2 v01 = {acc[ti][tj][0], acc[ti][tj][1]};
            const f32x2 v23 = {acc[ti][tj][2], acc[ti][tj][3]};
            f32x2 d01 = t01 - 2.0f * v01;
            f32x2 d23 = t23 - 2.0f * v23;
            d01 = __builtin_elementwise_max(d01, (f32x2){1.0f, 1.0f});
            d23 = __builtin_elementwise_max(d23, (f32x2){1.0f, 1.0f});
            pr *= d01; pr *= d23;
        }
        s += __logf(pr.x * pr.y);   // product of 8 dists <= (1.5e3)^8, fp32-safe
    }
    return s;
}

// diagonal-straddling tile: per-entry weight 2 (j>i) / 1 (j==i) / 0 (j<i)
__device__ __forceinline__ float logsumStraddle(const f32x4 (&acc)[4][2],
                                                const float* __restrict__ sqA,
                                                const float sb[2],
                                                int wr, int wc, int quad, int l15,
                                                int I0, int J0) {
    float s = 0.0f;
    #pragma unroll
    for (int ti = 0; ti < 4; ++ti) {
        #pragma unroll
        for (int tj = 0; tj < 2; ++tj) {
            const int j = J0 + wc * 32 + tj * 16 + l15;
            float pr = 1.0f;
            #pragma unroll
            for (int r = 0; r < 4; ++r) {
                const int i = I0 + wr * 64 + ti * 16 + quad * 4 + r;
                float d = fmaf(-2.0f, acc[ti][tj][r],
                               sqA[wr * 64 + ti * 16 + quad * 4 + r] + sb[tj]);
                d = fmaxf(d, 1.0f);
                const float t = (j > i) ? d : 1.0f;
                const float u = (j >= i) ? d : 1.0f;
                pr *= t * u;
            }
            s += __logf(pr);
        }
    }
    return s;
}

__global__ __launch_bounds__(256) void mqjs_main(
    const unsigned char* __restrict__ x1q, const unsigned char* __restrict__ x2q,
    const unsigned char* __restrict__ pq,
    const float* __restrict__ sq1, const float* __restrict__ sq2,
    const float* __restrict__ sqp, float* __restrict__ partials) {

    // ~33 KB LDS; A operands live entirely in registers
    __shared__ __align__(16) unsigned char BAs[2 * BJ * 128]; // p  J-tile, both kc (16 KB)
    __shared__ __align__(16) unsigned char BBs[2 * BJ * 128]; // x1 J-tile, both kc (16 KB)
    __shared__ float sqa1[BM], sqa2[BM];
    __shared__ float red[4];

    const int tid = threadIdx.x;
    const int lane = tid & 63;
    const int wv = tid >> 6;
    const int wr = wv >> 1, wc = wv & 1;      // wave quadrant: 64 I-rows x 32 J-cols
    const int quad = lane >> 4, l15 = lane & 15;

    const int I0 = blockIdx.y * BM;
    const int jbase = blockIdx.x * JG;
    const float wse = -(float)N / (float)(N - 1);

    const int srow = lane >> 3;
    const int sblk = (lane & 7) ^ srow;

    // stage first p J-tile; load sq rows
    stageB(pq, BAs,        jbase * BJ, 0,   wv, srow, sblk);
    stageB(pq, BAs + 8192, jbase * BJ, 128, wv, srow, sblk);
    if (tid < BM) sqa1[tid] = sq1[I0 + tid];
    else          sqa2[tid - BM] = sq2[I0 + tid - BM];

    // A fragments straight from global (32B/lane, 32-aligned, L2-resident; once per block)
    i32x8 a1f[2][4], a2f[2][4];
    #pragma unroll
    for (int kc = 0; kc < 2; ++kc)
        #pragma unroll
        for (int ti = 0; ti < 4; ++ti) {
            const size_t ro = (size_t)(I0 + wr * 64 + ti * 16 + l15) * D + kc * 128 + quad * 32;
            a1f[kc][ti] = *(const i32x8*)(x1q + ro);
            a2f[kc][ti] = *(const i32x8*)(x2q + ro);
        }
    __syncthreads();                          // BAs + sq arrays ready

    float tsum = 0.0f;

    for (int jj = 0; jj < JG; ++jj) {
        const int J0 = (jbase + jj) * BJ;
        const bool doSym = (J0 >= I0);
        const bool full  = (J0 >= I0 + BM);

        // ---- pass A: acc0 = x1.p^T, acc1 = x2.p^T (BAs holds p[jj])
        f32x4 acc0[4][2], acc1[4][2];
        #pragma unroll
        for (int a = 0; a < 4; ++a)
            #pragma unroll
            for (int b = 0; b < 2; ++b) {
                acc0[a][b] = (f32x4){0.f, 0.f, 0.f, 0.f};
                acc1[a][b] = (f32x4){0.f, 0.f, 0.f, 0.f};
            }
        #pragma unroll
        for (int kc = 0; kc < 2; ++kc) {
            i32x8 bfr[2];
            #pragma unroll
            for (int tj = 0; tj < 2; ++tj)
                bfr[tj] = read_frag(BAs + kc * 8192, wc * 32 + tj * 16 + l15, quad);
            #pragma unroll
            for (int ti = 0; ti < 4; ++ti)
                #pragma unroll
                for (int tj = 0; tj < 2; ++tj) {
                    acc0[ti][tj] = mfma8(a1f[kc][ti], bfr[tj], acc0[ti][tj]);
                    acc1[ti][tj] = mfma8(a2f[kc][ti], bfr[tj], acc1[ti][tj]);
                }
        }

        float sbp[2];
        #pragma unroll
        for (int tj = 0; tj < 2; ++tj) sbp[tj] = sqp[J0 + wc * 32 + tj * 16 + l15];

        if (doSym) {
            // stage x1[jj] into BBs; epilogue A covers the flight
            stageB(x1q, BBs,        J0, 0,   wv, srow, sblk);
            stageB(x1q, BBs + 8192, J0, 128, wv, srow, sblk);
            tsum += 0.5f * logsumP(acc0, sqa1, sbp, wr, quad);
            tsum += 0.5f * logsumP(acc1, sqa2, sbp, wr, quad);
            __syncthreads();                  // BBs ready; all waves done with BAs

            // ---- pass B: acc2 = x1.x1^T
            f32x4 acc2[4][2];
            #pragma unroll
            for (int a = 0; a < 4; ++a)
                #pragma unroll
                for (int b = 0; b < 2; ++b)
                    acc2[a][b] = (f32x4){0.f, 0.f, 0.f, 0.f};
            #pragma unroll
            for (int kc = 0; kc < 2; ++kc) {
                i32x8 bfr[2];
                #pragma unroll
                for (int tj = 0; tj < 2; ++tj)
                    bfr[tj] = read_frag(BBs + kc * 8192, wc * 32 + tj * 16 + l15, quad);
                #pragma unroll
                for (int ti = 0; ti < 4; ++ti)
                    #pragma unroll
                    for (int tj = 0; tj < 2; ++tj)
                        acc2[ti][tj] = mfma8(a1f[kc][ti], bfr[tj], acc2[ti][tj]);
            }
            if (jj < JG - 1) {                // restage BAs with p[jj+1]; epilogue covers
                stageB(pq, BAs,        (jbase + jj + 1) * BJ, 0,   wv, srow, sblk);
                stageB(pq, BAs + 8192, (jbase + jj + 1) * BJ, 128, wv, srow, sblk);
            }
            float sbx[2];
            #pragma unroll
            for (int tj = 0; tj < 2; ++tj) sbx[tj] = sq1[J0 + wc * 32 + tj * 16 + l15];
            if (full)
                tsum += wse * logsumP(acc2, sqa1, sbx, wr, quad);
            else
                tsum += 0.5f * wse * logsumStraddle(acc2, sqa1, sbx, wr, wc, quad, l15, I0, J0);
            __syncthreads();                  // BAs[jj+1] ready; BBs free
        } else {
            __syncthreads();                  // all waves done with BAs (cheap drain)
            if (jj < JG - 1) {                // restage BAs; epilogue A covers the flight
                stageB(pq, BAs,        (jbase + jj + 1) * BJ, 0,   wv, srow, sblk);
                stageB(pq, BAs + 8192, (jbase + jj + 1) * BJ, 128, wv, srow, sblk);
            }
            tsum += 0.5f * logsumP(acc0, sqa1, sbp, wr, quad);
            tsum += 0.5f * logsumP(acc1, sqa2, sbp, wr, quad);
            __syncthreads();                  // BAs[jj+1] ready
        }
    }

    #pragma unroll
    for (int o = 32; o > 0; o >>= 1) tsum += __shfl_down(tsum, o, 64);
    if (lane == 0) red[wv] = tsum;
    __syncthreads();
    if (tid == 0)
        partials[blockIdx.y * GJ + blockIdx.x] = red[0] + red[1] + red[2] + red[3];
}

// reduce 1024 partials (double accumulation) -> final scalar
__global__ void finalize_kernel(const float* __restrict__ partials, float* __restrict__ out) {
    const int tid = threadIdx.x;          // 256 threads
    const float4 v = ((const float4*)partials)[tid];
    double s = (double)v.x + (double)v.y + (double)v.z + (double)v.w;
    #pragma unroll
    for (int o = 32; o > 0; o >>= 1) s += __shfl_down(s, o, 64);
    __shared__ double r[4];
    if ((tid & 63) == 0) r[tid >> 6] = s;
    __syncthreads();
    if (tid == 0) out[0] = (float)((r[0] + r[1] + r[2] + r[3]) / (double)N);
}

extern "C" void kernel_launch(void* const* d_in, const int* in_sizes, int n_in,
                              void* d_out, int out_size, void* d_ws, size_t ws_size,
                              hipStream_t stream) {
    const float* x1 = (const float*)d_in[0];
    const float* x2 = (const float*)d_in[1];

    char* ws = (char*)d_ws;
    const size_t MBYTES = (size_t)N * D;                  // 2 MiB per fp8 matrix
    unsigned* x1q = (unsigned*)(ws);
    unsigned* x2q = (unsigned*)(ws + MBYTES);
    unsigned* pq  = (unsigned*)(ws + 2 * MBYTES);
    float* sq1 = (float*)(ws + 3 * MBYTES);
    float* sq2 = (float*)(ws + 3 * MBYTES + (size_t)N * 4);
    float* sqp = (float*)(ws + 3 * MBYTES + (size_t)N * 8);
    float* partials = (float*)(ws + 3 * MBYTES + (size_t)N * 12);

    prep_kernel<<<N / 4, 256, 0, stream>>>(x1, x2, x1q, x2q, pq, sq1, sq2, sqp);
    mqjs_main<<<dim3(GJ, GI), 256, 0, stream>>>(
        (const unsigned char*)x1q, (const unsigned char*)x2q, (const unsigned char*)pq,
        sq1, sq2, sqp, partials);
    finalize_kernel<<<1, 256, 0, stream>>>(partials, (float*)d_out);
}

// Round 11
// 144.284 us; speedup vs baseline: 1.2920x; 1.1529x over previous
//
#include <hip/hip_runtime.h>

#define N 8192
#define D 256
#define BM 128                    // I-tile rows
#define BJ 64                     // J-tile rows
#define JG 8                      // J-tiles per block
#define GJ (N / BJ / JG)          // 16
#define GI (N / BM)               // 64
#define NPART (3 * GI * GJ)       // 3072 partials

typedef int   i32x4 __attribute__((ext_vector_type(4)));
typedef int   i32x8 __attribute__((ext_vector_type(8)));
typedef float f32x4 __attribute__((ext_vector_type(4)));
typedef float f32x2 __attribute__((ext_vector_type(2)));

// -------- prep: fp32 -> fp8 e4m3 (packed), norms of the DEQUANTIZED values ----
__device__ __forceinline__ unsigned pack_fp8x4(float a, float b, float c, float d) {
    unsigned lo = __builtin_amdgcn_cvt_pk_fp8_f32(a, b, 0, false);
    return __builtin_amdgcn_cvt_pk_fp8_f32(c, d, lo, true);
}
__device__ __forceinline__ float dequant_sumsq(unsigned q) {
    const float v0 = __builtin_amdgcn_cvt_f32_fp8(q, 0);
    const float v1 = __builtin_amdgcn_cvt_f32_fp8(q, 1);
    const float v2 = __builtin_amdgcn_cvt_f32_fp8(q, 2);
    const float v3 = __builtin_amdgcn_cvt_f32_fp8(q, 3);
    return fmaf(v0, v0, fmaf(v1, v1, fmaf(v2, v2, v3 * v3)));
}

__global__ void prep_kernel(const float* __restrict__ x1, const float* __restrict__ x2,
                            unsigned* __restrict__ x1q, unsigned* __restrict__ x2q,
                            unsigned* __restrict__ pq,
                            float* __restrict__ sq1, float* __restrict__ sq2,
                            float* __restrict__ sqp) {
    const int tid = threadIdx.x, lane = tid & 63, wv = tid >> 6;
    const int row = blockIdx.x * 4 + wv;
    const size_t eb = (size_t)row * D + lane * 4;
    const float4 a = *(const float4*)(x1 + eb);
    const float4 b = *(const float4*)(x2 + eb);
    const float px = 0.5f * (a.x + b.x), py = 0.5f * (a.y + b.y);
    const float pz = 0.5f * (a.z + b.z), pw = 0.5f * (a.w + b.w);
    const unsigned qa = pack_fp8x4(a.x, a.y, a.z, a.w);
    const unsigned qb = pack_fp8x4(b.x, b.y, b.z, b.w);
    const unsigned qp = pack_fp8x4(px, py, pz, pw);
    const size_t wb = (size_t)row * (D / 4) + lane;
    x1q[wb] = qa; x2q[wb] = qb; pq[wb] = qp;
    float s1 = dequant_sumsq(qa), s2 = dequant_sumsq(qb), sp = dequant_sumsq(qp);
    #pragma unroll
    for (int o = 32; o > 0; o >>= 1) {
        s1 += __shfl_down(s1, o, 64);
        s2 += __shfl_down(s2, o, 64);
        sp += __shfl_down(sp, o, 64);
    }
    if (lane == 0) { sq1[row] = s1; sq2[row] = s2; sqp[row] = sp; }
}

// -------- main ---------------------------------------------------------------
__device__ __forceinline__ f32x4 mfma8(i32x8 a, i32x8 b, f32x4 c) {
    return __builtin_amdgcn_mfma_scale_f32_16x16x128_f8f6f4(
        a, b, c, 0, 0, 0, 0x7F7F7F7F, 0, 0x7F7F7F7F);
}

// B-fragment from LDS: 32 fp8 (k-chunk quad*32) of row m; 16B blocks XOR-swizzled by row&7
__device__ __forceinline__ i32x8 read_frag(const unsigned char* Ts, int m, int quad) {
    const int r7 = m & 7;
    const i32x4 lo = *(const i32x4*)(Ts + m * 128 + ((((2 * quad)     ^ r7)) << 4));
    const i32x4 hi = *(const i32x4*)(Ts + m * 128 + ((((2 * quad + 1) ^ r7)) << 4));
    i32x8 f;
    f[0] = lo[0]; f[1] = lo[1]; f[2] = lo[2]; f[3] = lo[3];
    f[4] = hi[0]; f[5] = hi[1]; f[6] = hi[2]; f[7] = hi[3];
    return f;
}

// stage a 64-row x 128B K-chunk (8 KB, 8 groups)
__device__ __forceinline__ void stageB(const unsigned char* __restrict__ g,
                                       unsigned char* s, int rowbase, size_t kb,
                                       int wv, int srow, int sblk) {
    #pragma unroll
    for (int it = 0; it < 2; ++it) {
        const int grp = wv * 2 + it;
        const int row = grp * 8 + srow;
        __builtin_amdgcn_global_load_lds(
            (const __attribute__((address_space(1))) void*)(g + (size_t)(rowbase + row) * D + kb + sblk * 16),
            (__attribute__((address_space(3))) void*)(s + grp * 1024), 16, 0, 0);
    }
}

// packed-f32 log-sum over 32 entries (4 ti x 2 tj x 4 regs); sa in registers
__device__ __forceinline__ float logsumP(const f32x4 (&acc)[4][2],
                                         const f32x2 (&sa01)[4], const f32x2 (&sa23)[4],
                                         const float sb[2]) {
    float s = 0.0f;
    #pragma unroll
    for (int ti = 0; ti < 4; ++ti) {
        f32x2 pr = {1.0f, 1.0f};
        #pragma unroll
        for (int tj = 0; tj < 2; ++tj) {
            const f32x2 sbv = {sb[tj], sb[tj]};
            const f32x2 t01 = sa01[ti] + sbv, t23 = sa23[ti] + sbv;
            const f32x2 v01 = {acc[ti][tj][0], acc[ti][tj][1]};
            const f32x2 v23 = {acc[ti][tj][2], acc[ti][tj][3]};
            f32x2 d01 = t01 - 2.0f * v01;
            f32x2 d23 = t23 - 2.0f * v23;
            d01 = __builtin_elementwise_max(d01, (f32x2){1.0f, 1.0f});
            d23 = __builtin_elementwise_max(d23, (f32x2){1.0f, 1.0f});
            pr *= d01; pr *= d23;
        }
        s += __logf(pr.x * pr.y);   // product of 8 dists <= (1.5e3)^8, fp32-safe
    }
    return s;
}

// diagonal-straddling tile: per-entry exponent 2 (j>i) / 1 (j==i) / 0 (j<i)
__device__ __forceinline__ float logsumStraddle(const f32x4 (&acc)[4][2],
                                                const f32x2 (&sa01)[4], const f32x2 (&sa23)[4],
                                                const float sb[2],
                                                int wr, int wc, int quad, int l15,
                                                int I0, int J0) {
    float s = 0.0f;
    #pragma unroll
    for (int ti = 0; ti < 4; ++ti) {
        #pragma unroll
        for (int tj = 0; tj < 2; ++tj) {
            const int j = J0 + wc * 32 + tj * 16 + l15;
            float pr = 1.0f;
            #pragma unroll
            for (int r = 0; r < 4; ++r) {
                const int i = I0 + wr * 64 + ti * 16 + quad * 4 + r;
                const float sav = (r < 2) ? ((r & 1) ? sa01[ti].y : sa01[ti].x)
                                          : ((r & 1) ? sa23[ti].y : sa23[ti].x);
                float d = fmaf(-2.0f, acc[ti][tj][r], sav + sb[tj]);
                d = fmaxf(d, 1.0f);
                const float t = (j > i) ? d : 1.0f;
                const float u = (j >= i) ? d : 1.0f;
                pr *= t * u;
            }
            s += __logf(pr);
        }
    }
    return s;
}

__global__ __launch_bounds__(256) void mqjs_main(
    const unsigned char* __restrict__ x1q, const unsigned char* __restrict__ x2q,
    const unsigned char* __restrict__ pq,
    const float* __restrict__ sq1, const float* __restrict__ sq2,
    const float* __restrict__ sqp, float* __restrict__ partials) {

    // 32 KB LDS: B J-tile double buffer only (A lives in registers)
    __shared__ __align__(16) unsigned char Bs[2][2 * BJ * 128];
    __shared__ float red[4];

    const int tid = threadIdx.x;
    const int lane = tid & 63;
    const int wv = tid >> 6;
    const int wr = wv >> 1, wc = wv & 1;      // wave: 64 I-rows x 32 J-cols
    const int quad = lane >> 4, l15 = lane & 15;
    const int srow = lane >> 3;
    const int sblk = (lane & 7) ^ srow;

    const int z = blockIdx.z;
    const int I0 = blockIdx.y * BM;
    const int jbase = blockIdx.x * JG;
    const int pid = (z * GI + blockIdx.y) * GJ + blockIdx.x;
    const float wse = -(float)N / (float)(N - 1);

    int jj0 = 0;
    if (z == 2) {                              // first J-tile touching j >= i
        jj0 = 2 * (int)blockIdx.y - jbase;
        if (jj0 < 0) jj0 = 0;
        if (jj0 >= JG) { if (tid == 0) partials[pid] = 0.0f; return; }
    }

    const unsigned char* Ag = (z == 1) ? x2q : x1q;
    const unsigned char* Bg = (z == 2) ? x1q : pq;
    const float* sqAg = (z == 1) ? sq2 : sq1;
    const float* sqBg = (z == 2) ? sq1 : sqp;

    // A fragments + sqA straight from global (once per block; L2-resident)
    i32x8 af[2][4];
    f32x2 sa01[4], sa23[4];
    #pragma unroll
    for (int ti = 0; ti < 4; ++ti) {
        #pragma unroll
        for (int kc = 0; kc < 2; ++kc) {
            const size_t ro = (size_t)(I0 + wr * 64 + ti * 16 + l15) * D + kc * 128 + quad * 32;
            af[kc][ti] = *(const i32x8*)(Ag + ro);
        }
        const int sbase = I0 + wr * 64 + ti * 16 + quad * 4;
        sa01[ti] = (f32x2){sqAg[sbase], sqAg[sbase + 1]};
        sa23[ti] = (f32x2){sqAg[sbase + 2], sqAg[sbase + 3]};
    }

    // stage first B tile into buf 0
    stageB(Bg, Bs[0],        (jbase + jj0) * BJ, 0,   wv, srow, sblk);
    stageB(Bg, Bs[0] + 8192, (jbase + jj0) * BJ, 128, wv, srow, sblk);
    __syncthreads();

    float tsum = 0.0f;

    for (int jj = jj0; jj < JG; ++jj) {
        const int J0 = (jbase + jj) * BJ;
        const int buf = (jj - jj0) & 1;

        float sb[2];                           // issue early; used after MFMAs
        #pragma unroll
        for (int tj = 0; tj < 2; ++tj) sb[tj] = sqBg[J0 + wc * 32 + tj * 16 + l15];

        f32x4 acc[4][2];
        #pragma unroll
        for (int a = 0; a < 4; ++a)
            #pragma unroll
            for (int b = 0; b < 2; ++b)
                acc[a][b] = (f32x4){0.f, 0.f, 0.f, 0.f};
        #pragma unroll
        for (int kc = 0; kc < 2; ++kc) {
            i32x8 bfr[2];
            #pragma unroll
            for (int tj = 0; tj < 2; ++tj)
                bfr[tj] = read_frag(Bs[buf] + kc * 8192, wc * 32 + tj * 16 + l15, quad);
            #pragma unroll
            for (int ti = 0; ti < 4; ++ti)
                #pragma unroll
                for (int tj = 0; tj < 2; ++tj)
                    acc[ti][tj] = mfma8(af[kc][ti], bfr[tj], acc[ti][tj]);
        }

        if (jj < JG - 1) {                     // prefetch next B; epilogue covers flight
            stageB(Bg, Bs[buf ^ 1],        (jbase + jj + 1) * BJ, 0,   wv, srow, sblk);
            stageB(Bg, Bs[buf ^ 1] + 8192, (jbase + jj + 1) * BJ, 128, wv, srow, sblk);
        }

        if (z < 2) {
            tsum += 0.5f * logsumP(acc, sa01, sa23, sb);
        } else if (J0 >= I0 + BM) {
            tsum += wse * logsumP(acc, sa01, sa23, sb);          // upper full: weight 2*0.5*wse
        } else {
            tsum += 0.5f * wse * logsumStraddle(acc, sa01, sa23, sb, wr, wc, quad, l15, I0, J0);
        }

        if (jj < JG - 1) __syncthreads();      // next buf staged; prev buf free
    }

    #pragma unroll
    for (int o = 32; o > 0; o >>= 1) tsum += __shfl_down(tsum, o, 64);
    if (lane == 0) red[wv] = tsum;
    __syncthreads();
    if (tid == 0) partials[pid] = red[0] + red[1] + red[2] + red[3];
}

// reduce 3072 partials (double accumulation) -> final scalar
__global__ void finalize_kernel(const float* __restrict__ partials, float* __restrict__ out) {
    const int tid = threadIdx.x;              // 768 threads
    const float4 v = ((const float4*)partials)[tid];
    double s = (double)v.x + (double)v.y + (double)v.z + (double)v.w;
    #pragma unroll
    for (int o = 32; o > 0; o >>= 1) s += __shfl_down(s, o, 64);
    __shared__ double r[12];
    if ((tid & 63) == 0) r[tid >> 6] = s;
    __syncthreads();
    if (tid == 0) {
        double t = 0.0;
        #pragma unroll
        for (int i = 0; i < 12; ++i) t += r[i];
        out[0] = (float)(t / (double)N);
    }
}

extern "C" void kernel_launch(void* const* d_in, const int* in_sizes, int n_in,
                              void* d_out, int out_size, void* d_ws, size_t ws_size,
                              hipStream_t stream) {
    const float* x1 = (const float*)d_in[0];
    const float* x2 = (const float*)d_in[1];

    char* ws = (char*)d_ws;
    const size_t MBYTES = (size_t)N * D;                  // 2 MiB per fp8 matrix
    unsigned* x1q = (unsigned*)(ws);
    unsigned* x2q = (unsigned*)(ws + MBYTES);
    unsigned* pq  = (unsigned*)(ws + 2 * MBYTES);
    float* sq1 = (float*)(ws + 3 * MBYTES);
    float* sq2 = (float*)(ws + 3 * MBYTES + (size_t)N * 4);
    float* sqp = (float*)(ws + 3 * MBYTES + (size_t)N * 8);
    float* partials = (float*)(ws + 3 * MBYTES + (size_t)N * 12);

    prep_kernel<<<N / 4, 256, 0, stream>>>(x1, x2, x1q, x2q, pq, sq1, sq2, sqp);
    mqjs_main<<<dim3(GJ, GI, 3), 256, 0, stream>>>(
        (const unsigned char*)x1q, (const unsigned char*)x2q, (const unsigned char*)pq,
        sq1, sq2, sqp, partials);
    finalize_kernel<<<1, 768, 0, stream>>>(partials, (float*)d_out);
}